// Round 1
// baseline (490.314 us; speedup 1.0000x reference)
//
#include <hip/hip_runtime.h>
#include <hip/hip_bf16.h>

#define B_DIM 512
#define T_DIM 512
#define IND 64
#define WIDTH 128
#define GAMMA 0.01f
#define EPS 0.01f

// ---------------------------------------------------------------------------
// Kernel 1: projection  out[m][w] = b[w] + sum_i x[m][i] * V[i][w]
// m = b*T + t, M = 262144. Tile: 8 rows x 128 cols per block-iteration.
// V staged in LDS as float2 pairs (c, c+64); x rows staged in LDS, read as
// float4 broadcasts. Writes straight into d_out (same layout as outputs).
// ---------------------------------------------------------------------------
#define K1_ROWS 8
#define K1_TILES ((B_DIM * T_DIM) / K1_ROWS)  // 32768

__global__ __launch_bounds__(256) void proj_kernel(
    const float* __restrict__ x, const float* __restrict__ V,
    const float* __restrict__ bias, float* __restrict__ out) {
  __shared__ float2 Vp[IND * 64];      // Vp[i*64+c] = (V[i][c], V[i][c+64]) 32KB
  __shared__ float bl[WIDTH];
  __shared__ float xs[K1_ROWS][IND];   // 2KB

  const int tid = threadIdx.x;
  // stage V as pairs
  for (int p = tid; p < IND * 64; p += 256) {
    int i = p >> 6, c = p & 63;
    Vp[p] = make_float2(V[i * WIDTH + c], V[i * WIDTH + c + 64]);
  }
  if (tid < WIDTH) bl[tid] = bias[tid];
  __syncthreads();

  const int c = tid & 63;        // column (and column+64)
  const int rh = tid >> 6;       // 0..3 -> rows rh and rh+4

  for (int tile = blockIdx.x; tile < K1_TILES; tile += gridDim.x) {
    const int m0 = tile * K1_ROWS;
    __syncthreads();  // protect xs from previous tile's readers
    // stage 8 rows of x: 512 consecutive floats, 2 per thread (coalesced)
    ((float*)xs)[tid] = x[(size_t)m0 * IND + tid];
    ((float*)xs)[tid + 256] = x[(size_t)m0 * IND + tid + 256];
    __syncthreads();

    float acc00 = bl[c], acc01 = bl[c + 64];
    float acc10 = bl[c], acc11 = bl[c + 64];

    const float4* xa4 = (const float4*)(&xs[rh][0]);
    const float4* xb4 = (const float4*)(&xs[rh + 4][0]);
#pragma unroll
    for (int i4 = 0; i4 < IND / 4; ++i4) {
      float4 xa = xa4[i4];  // broadcast across wave (same addr)
      float4 xb = xb4[i4];
#pragma unroll
      for (int j = 0; j < 4; ++j) {
        float xav = (j == 0) ? xa.x : (j == 1) ? xa.y : (j == 2) ? xa.z : xa.w;
        float xbv = (j == 0) ? xb.x : (j == 1) ? xb.y : (j == 2) ? xb.z : xb.w;
        float2 v = Vp[(i4 * 4 + j) * 64 + c];
        acc00 += xav * v.x;
        acc01 += xav * v.y;
        acc10 += xbv * v.x;
        acc11 += xbv * v.y;
      }
    }
    float* o0 = out + (size_t)(m0 + rh) * WIDTH;
    float* o1 = out + (size_t)(m0 + rh + 4) * WIDTH;
    o0[c] = acc00;
    o0[c + 64] = acc01;
    o1[c] = acc10;
    o1[c + 64] = acc11;
  }
}

// ---------------------------------------------------------------------------
// Kernel 2: sequential recurrence, one block per batch row.
// Thread w holds A[:,w] in 128 VGPRs; state row in LDS (broadcast reads).
// u is read from d_out (projection result) and overwritten in place.
// ---------------------------------------------------------------------------
__global__ __launch_bounds__(128) void rnn_kernel(
    const float* __restrict__ W, const float* __restrict__ init,
    float* __restrict__ out, float* __restrict__ finals) {
  __shared__ float sL[WIDTH];
  const int b = blockIdx.x;
  const int w = threadIdx.x;

  // A[:,w] = W[:,w] - W[w,:]
  float Areg[WIDTH];
#pragma unroll
  for (int k = 0; k < WIDTH; ++k) Areg[k] = W[k * WIDTH + w];  // coalesced cols
  const float4* Wrow = (const float4*)(W + (size_t)w * WIDTH);
#pragma unroll
  for (int k4 = 0; k4 < WIDTH / 4; ++k4) {
    float4 r = Wrow[k4];
    Areg[4 * k4 + 0] -= r.x;
    Areg[4 * k4 + 1] -= r.y;
    Areg[4 * k4 + 2] -= r.z;
    Areg[4 * k4 + 3] -= r.w;
  }

  float s = init[(size_t)b * WIDTH + w];
  sL[w] = s;
  __syncthreads();

  float* outb = out + (size_t)b * T_DIM * WIDTH + w;
  float u_next = outb[0];

#pragma unroll 1
  for (int t = 0; t < T_DIM; ++t) {
    float u = u_next;
    if (t < T_DIM - 1) u_next = outb[(size_t)(t + 1) * WIDTH];  // prefetch

    float acc0 = 0.f, acc1 = 0.f, acc2 = 0.f, acc3 = 0.f;
    const float4* s4 = (const float4*)sL;
#pragma unroll
    for (int k4 = 0; k4 < WIDTH / 4; ++k4) {
      float4 sv = s4[k4];  // same addr for all lanes -> LDS broadcast
      acc0 += sv.x * Areg[4 * k4 + 0];
      acc1 += sv.y * Areg[4 * k4 + 1];
      acc2 += sv.z * Areg[4 * k4 + 2];
      acc3 += sv.w * Areg[4 * k4 + 3];
    }
    float f = ((acc0 + acc1) + (acc2 + acc3)) - GAMMA * s + u;

    // tanh(f) = sign(f) * (1 - e) / (1 + e), e = exp(-2|f|)   (NaN-safe)
    float af = fabsf(f);
    float e = __expf(-2.0f * af);
    float th = (1.0f - e) * __builtin_amdgcn_rcpf(1.0f + e);
    th = copysignf(th, f);

    float ns = s + EPS * th;
    outb[(size_t)t * WIDTH] = ns;  // overwrite u slot with output state

    __syncthreads();  // all dot-reads of sL done
    sL[w] = ns;
    s = ns;
    __syncthreads();  // new state visible
  }

  finals[(size_t)b * WIDTH + w] = s;
}

extern "C" void kernel_launch(void* const* d_in, const int* in_sizes, int n_in,
                              void* d_out, int out_size, void* d_ws,
                              size_t ws_size, hipStream_t stream) {
  const float* x = (const float*)d_in[0];
  const float* init = (const float*)d_in[1];
  const float* W = (const float*)d_in[2];
  const float* V = (const float*)d_in[3];
  const float* bias = (const float*)d_in[4];

  float* out = (float*)d_out;
  float* finals = out + (size_t)B_DIM * T_DIM * WIDTH;

  proj_kernel<<<2048, 256, 0, stream>>>(x, V, bias, out);
  rnn_kernel<<<B_DIM, 128, 0, stream>>>(W, init, out, finals);
}

// Round 2
// 328.004 us; speedup vs baseline: 1.4948x; 1.4948x over previous
//
#include <hip/hip_runtime.h>
#include <hip/hip_bf16.h>

#define B_DIM 512
#define T_DIM 512
#define IND 64
#define WIDTH 128
#define GAMMA 0.01f
#define EPS 0.01f

// ---------------------------------------------------------------------------
// Kernel 1: projection  out[m][w] = b[w] + sum_i x[m][i] * V[i][w]
// V column-pair held in registers (thread owns cols 2c, 2c+1); x staged in
// LDS 16 rows at a time, read as float4 wave-broadcasts. float2 stores.
// ---------------------------------------------------------------------------
#define PJ_ROWS 16
#define PJ_NT ((B_DIM * T_DIM) / PJ_ROWS)  // 16384

__global__ __launch_bounds__(256) void proj_kernel(
    const float* __restrict__ x, const float* __restrict__ V,
    const float* __restrict__ bias, float* __restrict__ out) {
  __shared__ __align__(16) float xs[PJ_ROWS * IND];  // 4 KB

  const int tid = threadIdx.x;
  const int c2 = (tid & 63) * 2;  // column pair
  const int rh = tid >> 6;        // 0..3 row slot

  float2 Vreg[IND];  // 128 VGPRs: V[k][c2], V[k][c2+1]
#pragma unroll
  for (int k = 0; k < IND; ++k)
    Vreg[k] = *(const float2*)(V + k * WIDTH + c2);
  const float2 bb = *(const float2*)(bias + c2);

  for (int tile = blockIdx.x; tile < PJ_NT; tile += gridDim.x) {
    const size_t m0 = (size_t)tile * PJ_ROWS;
    __syncthreads();  // protect xs from previous tile's readers
#pragma unroll
    for (int q = 0; q < 4; ++q)
      xs[tid + 256 * q] = x[m0 * IND + tid + 256 * q];
    __syncthreads();

    float2 acc0 = bb, acc1 = bb, acc2 = bb, acc3 = bb;
#pragma unroll
    for (int k4 = 0; k4 < IND / 4; ++k4) {
      float4 xv0 = ((const float4*)&xs[(rh + 0) * IND])[k4];  // broadcast
      float4 xv1 = ((const float4*)&xs[(rh + 4) * IND])[k4];
      float4 xv2 = ((const float4*)&xs[(rh + 8) * IND])[k4];
      float4 xv3 = ((const float4*)&xs[(rh + 12) * IND])[k4];
#pragma unroll
      for (int j = 0; j < 4; ++j) {
        float2 v = Vreg[4 * k4 + j];
        float e0 = (j == 0) ? xv0.x : (j == 1) ? xv0.y : (j == 2) ? xv0.z : xv0.w;
        float e1 = (j == 0) ? xv1.x : (j == 1) ? xv1.y : (j == 2) ? xv1.z : xv1.w;
        float e2 = (j == 0) ? xv2.x : (j == 1) ? xv2.y : (j == 2) ? xv2.z : xv2.w;
        float e3 = (j == 0) ? xv3.x : (j == 1) ? xv3.y : (j == 2) ? xv3.z : xv3.w;
        acc0.x += e0 * v.x; acc0.y += e0 * v.y;
        acc1.x += e1 * v.x; acc1.y += e1 * v.y;
        acc2.x += e2 * v.x; acc2.y += e2 * v.y;
        acc3.x += e3 * v.x; acc3.y += e3 * v.y;
      }
    }
    *(float2*)(out + (m0 + rh + 0) * WIDTH + c2) = acc0;
    *(float2*)(out + (m0 + rh + 4) * WIDTH + c2) = acc1;
    *(float2*)(out + (m0 + rh + 8) * WIDTH + c2) = acc2;
    *(float2*)(out + (m0 + rh + 12) * WIDTH + c2) = acc3;
  }
}

// ---------------------------------------------------------------------------
// Kernel 2: recurrence. 512 threads/block = (column c, k-chunk kc), 4-way
// split-k. A fragment (32 floats) in registers, stored ROTATED so the dot
// loop's register indices are compile-time while each kc group reads LDS
// float4s in a bank-staggered order. Double-buffered state -> 1 barrier/step.
// Depth-2 prefetch of u from global.
// ---------------------------------------------------------------------------
__global__ __launch_bounds__(512) void rnn_kernel(
    const float* __restrict__ W, const float* __restrict__ init,
    float* __restrict__ out, float* __restrict__ finals) {
  __shared__ __align__(16) float sL[2][WIDTH];
  const int b = blockIdx.x;
  const int tid = threadIdx.x;
  const int c = tid >> 2;   // 0..127 output column
  const int kc = tid & 3;   // k-chunk (lane bits 0-1)

  // Areg[4*j+m] = A[kc*32 + ((j+2*kc)&7)*4 + m][c],  A = W - W^T
  float Areg[32];
  {
    const int chunk = kc * 32;
#pragma unroll
    for (int j = 0; j < 8; ++j) {
      const int ri = (j + 2 * kc) & 7;  // runtime, used only in addresses
      const int k = chunk + ri * 4;
      float4 wr = *(const float4*)(W + (size_t)c * WIDTH + k);  // W[c][k..k+3]
      Areg[4 * j + 0] = W[(size_t)(k + 0) * WIDTH + c] - wr.x;
      Areg[4 * j + 1] = W[(size_t)(k + 1) * WIDTH + c] - wr.y;
      Areg[4 * j + 2] = W[(size_t)(k + 2) * WIDTH + c] - wr.z;
      Areg[4 * j + 3] = W[(size_t)(k + 3) * WIDTH + c] - wr.w;
    }
  }

  float s = init[(size_t)b * WIDTH + c];
  if (kc == 0) sL[0][c] = s;
  __syncthreads();

  float* outc = out + (size_t)b * T_DIM * WIDTH + c;
  float u0 = outc[0];
  float u1 = outc[WIDTH];

  const int base = kc * 8;  // float4 index of this thread's chunk
#pragma unroll 1
  for (int t = 0; t < T_DIM; ++t) {
    const int p = t & 1;
    const float u = u0;
    u0 = u1;
    if (t + 2 < T_DIM) u1 = outc[(size_t)(t + 2) * WIDTH];

    const float4* sp = (const float4*)&sL[p][0];
    float a0 = 0.f, a1 = 0.f, a2 = 0.f, a3 = 0.f;
#pragma unroll
    for (int j = 0; j < 8; ++j) {
      const int ri = (j + 2 * kc) & 7;  // bank-staggered across kc groups
      float4 sv = sp[base + ri];
      a0 += sv.x * Areg[4 * j + 0];
      a1 += sv.y * Areg[4 * j + 1];
      a2 += sv.z * Areg[4 * j + 2];
      a3 += sv.w * Areg[4 * j + 3];
    }
    float dot = (a0 + a1) + (a2 + a3);
    dot += __shfl_xor(dot, 1);  // sum over kc bit 0
    dot += __shfl_xor(dot, 2);  // sum over kc bit 1

    const float f = dot - GAMMA * s + u;
    // tanh(f) = sign(f) * (1 - e) / (1 + e), e = exp(-2|f|)  (NaN-safe)
    const float af = fabsf(f);
    const float e = __expf(-2.0f * af);
    float th = (1.0f - e) * __builtin_amdgcn_rcpf(1.0f + e);
    th = copysignf(th, f);
    const float ns = fmaf(EPS, th, s);

    if (kc == 0) {
      outc[(size_t)t * WIDTH] = ns;  // overwrite u slot with output state
      sL[p ^ 1][c] = ns;
    }
    s = ns;
    __syncthreads();  // new state visible; old buffer free to overwrite
  }

  if (kc == 0) finals[(size_t)b * WIDTH + c] = s;
}

extern "C" void kernel_launch(void* const* d_in, const int* in_sizes, int n_in,
                              void* d_out, int out_size, void* d_ws,
                              size_t ws_size, hipStream_t stream) {
  const float* x = (const float*)d_in[0];
  const float* init = (const float*)d_in[1];
  const float* W = (const float*)d_in[2];
  const float* V = (const float*)d_in[3];
  const float* bias = (const float*)d_in[4];

  float* out = (float*)d_out;
  float* finals = out + (size_t)B_DIM * T_DIM * WIDTH;

  proj_kernel<<<2048, 256, 0, stream>>>(x, V, bias, out);
  rnn_kernel<<<B_DIM, 512, 0, stream>>>(W, init, out, finals);
}

// Round 3
// 301.803 us; speedup vs baseline: 1.6246x; 1.0868x over previous
//
#include <hip/hip_runtime.h>
#include <hip/hip_bf16.h>

#define B_DIM 512
#define T_DIM 512
#define IND 64
#define WIDTH 128
#define GAMMA 0.01f
#define EPS 0.01f

// ---------------------------------------------------------------------------
// Kernel 1: projection  out[m][w] = b[w] + sum_i x[m][i] * V[i][w]
// (unchanged from R2: ~40 us, near BW roofline)
// ---------------------------------------------------------------------------
#define PJ_ROWS 16
#define PJ_NT ((B_DIM * T_DIM) / PJ_ROWS)  // 16384

__global__ __launch_bounds__(256) void proj_kernel(
    const float* __restrict__ x, const float* __restrict__ V,
    const float* __restrict__ bias, float* __restrict__ out) {
  __shared__ __align__(16) float xs[PJ_ROWS * IND];  // 4 KB

  const int tid = threadIdx.x;
  const int c2 = (tid & 63) * 2;  // column pair
  const int rh = tid >> 6;        // 0..3 row slot

  float2 Vreg[IND];  // V[k][c2], V[k][c2+1]
#pragma unroll
  for (int k = 0; k < IND; ++k)
    Vreg[k] = *(const float2*)(V + k * WIDTH + c2);
  const float2 bb = *(const float2*)(bias + c2);

  for (int tile = blockIdx.x; tile < PJ_NT; tile += gridDim.x) {
    const size_t m0 = (size_t)tile * PJ_ROWS;
    __syncthreads();
#pragma unroll
    for (int q = 0; q < 4; ++q)
      xs[tid + 256 * q] = x[m0 * IND + tid + 256 * q];
    __syncthreads();

    float2 acc0 = bb, acc1 = bb, acc2 = bb, acc3 = bb;
#pragma unroll
    for (int k4 = 0; k4 < IND / 4; ++k4) {
      float4 xv0 = ((const float4*)&xs[(rh + 0) * IND])[k4];
      float4 xv1 = ((const float4*)&xs[(rh + 4) * IND])[k4];
      float4 xv2 = ((const float4*)&xs[(rh + 8) * IND])[k4];
      float4 xv3 = ((const float4*)&xs[(rh + 12) * IND])[k4];
#pragma unroll
      for (int j = 0; j < 4; ++j) {
        float2 v = Vreg[4 * k4 + j];
        float e0 = (j == 0) ? xv0.x : (j == 1) ? xv0.y : (j == 2) ? xv0.z : xv0.w;
        float e1 = (j == 0) ? xv1.x : (j == 1) ? xv1.y : (j == 2) ? xv1.z : xv1.w;
        float e2 = (j == 0) ? xv2.x : (j == 1) ? xv2.y : (j == 2) ? xv2.z : xv2.w;
        float e3 = (j == 0) ? xv3.x : (j == 1) ? xv3.y : (j == 2) ? xv3.z : xv3.w;
        acc0.x += e0 * v.x; acc0.y += e0 * v.y;
        acc1.x += e1 * v.x; acc1.y += e1 * v.y;
        acc2.x += e2 * v.x; acc2.y += e2 * v.y;
        acc3.x += e3 * v.x; acc3.y += e3 * v.y;
      }
    }
    *(float2*)(out + (m0 + rh + 0) * WIDTH + c2) = acc0;
    *(float2*)(out + (m0 + rh + 4) * WIDTH + c2) = acc1;
    *(float2*)(out + (m0 + rh + 8) * WIDTH + c2) = acc2;
    *(float2*)(out + (m0 + rh + 12) * WIDTH + c2) = acc3;
  }
}

// ---------------------------------------------------------------------------
// Kernel 2: recurrence. 256 threads/block: thread = (colpair cp in 0..63,
// k-chunk kc in lane bits 0-1). 2 output columns per thread -> half the LDS
// reads of R2. Split-k reduction via quad_perm DPP adds (VALU, not LDS pipe).
// Double-buffered state, 1 barrier/step, depth-2 global prefetch of u.
// ---------------------------------------------------------------------------
template <int CTRL>
__device__ __forceinline__ float dpp_mov(float x) {
  return __int_as_float(
      __builtin_amdgcn_update_dpp(0, __float_as_int(x), CTRL, 0xf, 0xf, true));
}

__global__ __launch_bounds__(256) void rnn_kernel(
    const float* __restrict__ W, const float* __restrict__ init,
    float* __restrict__ out, float* __restrict__ finals) {
  __shared__ __align__(16) float sL[2][WIDTH];
  const int b = blockIdx.x;
  const int tid = threadIdx.x;
  const int kc = tid & 3;        // k-chunk, lane bits 0-1
  const int cp = tid >> 2;       // 0..63 column pair
  const int c0 = 2 * cp;         // columns c0, c0+1

  // Areg[col][4j+m] = A[kc*32 + ((j+2kc)&7)*4 + m][c0+col],  A = W - W^T
  // (rotation baked in so dot-loop register indices are compile-time)
  float Areg[2][32];
  {
    const int k0 = kc * 32;
#pragma unroll
    for (int j = 0; j < 8; ++j) {
      const int ri = (j + 2 * kc) & 7;  // runtime, addresses only
      const int k = k0 + ri * 4;
#pragma unroll
      for (int col = 0; col < 2; ++col) {
        const int cc = c0 + col;
        float4 wr = *(const float4*)(W + (size_t)cc * WIDTH + k);  // W[cc][k..]
        Areg[col][4 * j + 0] = W[(size_t)(k + 0) * WIDTH + cc] - wr.x;
        Areg[col][4 * j + 1] = W[(size_t)(k + 1) * WIDTH + cc] - wr.y;
        Areg[col][4 * j + 2] = W[(size_t)(k + 2) * WIDTH + cc] - wr.z;
        Areg[col][4 * j + 3] = W[(size_t)(k + 3) * WIDTH + cc] - wr.w;
      }
    }
  }

  float2 s = *(const float2*)(init + (size_t)b * WIDTH + c0);
  if (kc == 0) *(float2*)&sL[0][c0] = s;
  __syncthreads();

  const float* uc = out + (size_t)b * T_DIM * WIDTH + c0;
  float* outc = out + (size_t)b * T_DIM * WIDTH + c0;
  float2 u0 = *(const float2*)(uc);
  float2 u1 = *(const float2*)(uc + WIDTH);

#pragma unroll 1
  for (int t = 0; t < T_DIM; ++t) {
    const int p = t & 1;
    const float2 u = u0;
    u0 = u1;
    if (t + 2 < T_DIM) u1 = *(const float2*)(uc + (size_t)(t + 2) * WIDTH);

    const float4* sp = (const float4*)&sL[p][0];
    float a00 = 0.f, a01 = 0.f, a10 = 0.f, a11 = 0.f;
#pragma unroll
    for (int j = 0; j < 8; ++j) {
      const int ri = (j + 2 * kc) & 7;  // bank-staggered across kc groups
      float4 sv = sp[kc * 8 + ri];
      a00 += sv.x * Areg[0][4 * j + 0];
      a01 += sv.y * Areg[0][4 * j + 1];
      a00 += sv.z * Areg[0][4 * j + 2];
      a01 += sv.w * Areg[0][4 * j + 3];
      a10 += sv.x * Areg[1][4 * j + 0];
      a11 += sv.y * Areg[1][4 * j + 1];
      a10 += sv.z * Areg[1][4 * j + 2];
      a11 += sv.w * Areg[1][4 * j + 3];
    }
    float d0 = a00 + a01;
    float d1 = a10 + a11;
    // 4-way split-k sum over lane bits 0-1 via DPP (pure VALU)
    d0 += dpp_mov<0xB1>(d0);  // quad_perm [1,0,3,2]  (xor 1)
    d1 += dpp_mov<0xB1>(d1);
    d0 += dpp_mov<0x4E>(d0);  // quad_perm [2,3,0,1]  (xor 2)
    d1 += dpp_mov<0x4E>(d1);

    const float f0 = d0 - GAMMA * s.x + u.x;
    const float f1 = d1 - GAMMA * s.y + u.y;
    // tanh(f) = 1 - 2/(exp(2f)+1); inf-safe both directions
    const float e0 = __expf(2.0f * f0);
    const float e1 = __expf(2.0f * f1);
    const float th0 = fmaf(-2.0f, __builtin_amdgcn_rcpf(e0 + 1.0f), 1.0f);
    const float th1 = fmaf(-2.0f, __builtin_amdgcn_rcpf(e1 + 1.0f), 1.0f);
    s.x = fmaf(EPS, th0, s.x);
    s.y = fmaf(EPS, th1, s.y);

    if (kc == 0) {
      *(float2*)(outc + (size_t)t * WIDTH) = s;  // overwrite u slot
      *(float2*)&sL[p ^ 1][c0] = s;
    }
    __syncthreads();  // new state visible; old buffer free next step
  }

  if (kc == 0) *(float2*)(finals + (size_t)b * WIDTH + c0) = s;
}

extern "C" void kernel_launch(void* const* d_in, const int* in_sizes, int n_in,
                              void* d_out, int out_size, void* d_ws,
                              size_t ws_size, hipStream_t stream) {
  const float* x = (const float*)d_in[0];
  const float* init = (const float*)d_in[1];
  const float* W = (const float*)d_in[2];
  const float* V = (const float*)d_in[3];
  const float* bias = (const float*)d_in[4];

  float* out = (float*)d_out;
  float* finals = out + (size_t)B_DIM * T_DIM * WIDTH;

  proj_kernel<<<2048, 256, 0, stream>>>(x, V, bias, out);
  rnn_kernel<<<B_DIM, 256, 0, stream>>>(W, init, out, finals);
}